// Round 5
// baseline (1624.582 us; speedup 1.0000x reference)
//
#include <hip/hip_runtime.h>
#include <hip/hip_bf16.h>

// Flash attention fwd, B=4 H=16 S=2048 D=128. fp32 in/out.
// Round-8: LDS-pipe relief. Per-CU accounting at 483us showed the LDS pipe
// ~85% busy (b128 reads 3200cyc/slot + staging 768 + __shfl_xor ds_swizzles
// ~1550 + P writes + conflicts) while MFMA=26%/VALU=30%. Two changes:
//   1) Softmax row-max reduce moved off the LDS pipe: the 16-lane reduce
//      domain is exactly a DPP row, so use VALU DPP steps (quad_perm ^1,^2,
//      row_half_mirror, row_mirror) instead of 4x ds_swizzle per row.
//      Final L-sum reduce likewise. Removes 16 DS ops/wave-iter.
//   2) Vs pitch 40->32 (read stays balanced: group=(4*l16+quad)%8, 8
//      lanes/group; staging write becomes linear) -> LDS 30720 B/block ->
//      5 blocks/CU (20 waves) instead of 4.
// Everything else identical to the verified 483us round-7 kernel: prepacked
// bf16 K hi/lo + V^T in d_ws, reg-prefetch staging, split-bf16 QK^T,
// exp2-domain defer-max online softmax (THR=8), setprio around MFMA,
// head-affinity XCD swizzle.

typedef __bf16 bf16;
typedef __attribute__((ext_vector_type(4))) __bf16 bf16x4;
typedef __attribute__((ext_vector_type(8))) __bf16 bf16x8;
typedef __attribute__((ext_vector_type(4))) float f32x4;

constexpr int S_  = 2048;
constexpr int D_  = 128;
constexpr int BM  = 64;       // Q rows per block (4 waves x 16)
constexpr int BN  = 32;       // K/V rows per tile
constexpr int NIT = S_ / BN;  // 64
constexpr int PK  = D_ + 8;   // 136 bf16 K pitch (balanced bank groups)
constexpr int PVT = 32;       // V^T pitch (balanced: group=(4*l16+quad)%8)
constexpr int PP  = BN + 8;   // 40 bf16 P pitch

// bf16-element offsets of the packed images inside d_ws
constexpr size_t WS_KL   = 16777216;   // Klo image at +32 MB
constexpr size_t WS_VT   = 33554432;   // V^T image at +64 MB
constexpr size_t WS_NEED = 100663296;  // 96 MB total (bytes)

// ---- DPP 16-lane (one DPP row) reductions, zero LDS-pipe traffic ----
template <int CTRL>
__device__ __forceinline__ float dpp_fmax_step(float x) {
    int yi = __builtin_amdgcn_update_dpp(
        __float_as_int(x), __float_as_int(x), CTRL, 0xf, 0xf, false);
    return fmaxf(x, __int_as_float(yi));
}
template <int CTRL>
__device__ __forceinline__ float dpp_fadd_step(float x) {
    int yi = __builtin_amdgcn_update_dpp(
        __float_as_int(x), __float_as_int(x), CTRL, 0xf, 0xf, false);
    return x + __int_as_float(yi);
}
__device__ __forceinline__ float row16_max(float x) {
    x = dpp_fmax_step<0xB1>(x);   // quad_perm [1,0,3,2]  (lane^1)
    x = dpp_fmax_step<0x4E>(x);   // quad_perm [2,3,0,1]  (lane^2)
    x = dpp_fmax_step<0x141>(x);  // row_half_mirror      (combine 4s -> 8)
    x = dpp_fmax_step<0x140>(x);  // row_mirror           (combine 8s -> 16)
    return x;
}
__device__ __forceinline__ float row16_sum(float x) {
    x = dpp_fadd_step<0xB1>(x);
    x = dpp_fadd_step<0x4E>(x);
    x = dpp_fadd_step<0x141>(x);
    x = dpp_fadd_step<0x140>(x);
    return x;
}

// ---- pre-pack ----
// Kh/Kl images: [head][s][d] bf16, pitch 128 (tile it = 4096-elem block).
// V^T image: [head][tile][d][32] bf16 (per (head,tile) 4096 elems).
__global__ __launch_bounds__(256) void prepack(
    const float* __restrict__ kg, const float* __restrict__ vg,
    bf16* __restrict__ ws)
{
    const int gid = blockIdx.x * 256 + threadIdx.x;
    if (gid < 2097152) {                  // K: (64*2048 rows) x 16 chunks
        const int u  = gid & 15;
        const int rg = gid >> 4;          // head*2048 + s
        const float* src = kg + (size_t)rg * D_ + (u << 3);
        float x[8];
        *(float4*)&x[0] = *(const float4*)src;
        *(float4*)&x[4] = *(const float4*)(src + 4);
        bf16x8 h8, l8;
#pragma unroll
        for (int j = 0; j < 8; ++j) {
            bf16 h = (bf16)x[j];
            h8[j] = h;
            l8[j] = (bf16)(x[j] - (float)h);
        }
        const size_t di = (size_t)rg * 128 + (u << 3);
        *(bf16x8*)&ws[di]         = h8;
        *(bf16x8*)&ws[WS_KL + di] = l8;
    } else {                              // V: 4096 (head,tile) x 512 tasks
        const int g2 = gid - 2097152;
        const int i  = g2 & 511;
        const int tg = g2 >> 9;           // head*64 + tile
        const int p  = i & 15;            // t-pair: rows 2p, 2p+1
        const int c  = i >> 4;            // 0..31: cols 4c..4c+3
        const float* src = vg + ((size_t)tg * BN + 2 * p) * D_ + c * 4;
        float4 a0 = *(const float4*)src;
        float4 a1 = *(const float4*)(src + D_);
        const float* x0 = (const float*)&a0;
        const float* x1 = (const float*)&a1;
        bf16* vt = ws + WS_VT + (size_t)tg * 4096;
#pragma unroll
        for (int j = 0; j < 4; ++j) {
            union { ushort2 u2; bf16 b[2]; } pr;
            pr.b[0] = (bf16)x0[j];
            pr.b[1] = (bf16)x1[j];
            *(ushort2*)&vt[(c * 4 + j) * BN + 2 * p] = pr.u2;
        }
    }
}

// ---- main kernel: 4 waves x 16 Q-rows, 30 KB LDS -> 5 blocks/CU ----
__global__ __launch_bounds__(256, 5) void attn_fwd(
    const float* __restrict__ q, const bf16* __restrict__ ws,
    const float* __restrict__ sc, float* __restrict__ out)
{
    __shared__ __align__(16) bf16 Kh[BN * PK];      // 8704 B
    __shared__ __align__(16) bf16 Kl[BN * PK];      // 8704 B
    __shared__ __align__(16) bf16 Vs[D_ * PVT];     // 8192 B (Vs[d][t])
    __shared__ __align__(16) bf16 Ps[4 * 16 * PP];  // 5120 B (wave-private)
    // total 30720 B -> 5 blocks/CU, 20 waves/CU

    const int tid  = threadIdx.x;
    const int wave = tid >> 6;
    const int lane = tid & 63;
    const int l16  = lane & 15;
    const int quad = lane >> 4;

    // head-affinity XCD swizzle: 2048 blocks; XCD (bid&7) gets heads 8x..8x+7
    const int bid = blockIdx.x;
    const int idx = bid >> 3;                        // 0..255
    const int bh  = ((bid & 7) << 3) | (idx >> 5);   // head 0..63
    const int qt  = idx & 31;                        // Q tile 0..31

    const float scale = sc[bh] * 1.44269504088896f;  // fold log2(e)

    const float* qbase = q + ((size_t)bh * S_ + (size_t)qt * BM) * D_;
    const bf16* khp = ws +         (size_t)bh * 262144 + tid * 8;
    const bf16* klp = ws + WS_KL + (size_t)bh * 262144 + tid * 8;
    const bf16* vtp = ws + WS_VT + (size_t)bh * 262144 + tid * 8;

    // Q fragments (A-layout: m=l16, k=quad*8+j, +32*ks), scale folded, hi/lo
    bf16x8 qh[4], ql[4];
    {
        const float* qrow = qbase + (size_t)(wave * 16 + l16) * D_ + quad * 8;
#pragma unroll
        for (int ks = 0; ks < 4; ++ks) {
            float x[8];
            *(float4*)&x[0] = *(const float4*)(qrow + ks * 32);
            *(float4*)&x[4] = *(const float4*)(qrow + ks * 32 + 4);
#pragma unroll
            for (int j = 0; j < 8; ++j) {
                float xs = x[j] * scale;
                bf16 h = (bf16)xs;
                qh[ks][j] = h;
                ql[ks][j] = (bf16)(xs - (float)h);
            }
        }
    }

    f32x4 O[8];                  // O[dblk][r]: row=quad*4+r, col=l16+16*dblk
#pragma unroll
    for (int i = 0; i < 8; ++i) O[i] = (f32x4){0.f, 0.f, 0.f, 0.f};
    float mrow[4] = {-1e30f, -1e30f, -1e30f, -1e30f};
    float Lp[4]   = {0.f, 0.f, 0.f, 0.f};   // per-lane partial row sums

    // prefetch registers: 6 x 16 B held across one full compute phase
    bf16x8 rKh[2], rKl[2], rVt[2];

#define LOADT(t)                                                          \
    {                                                                     \
        const size_t toff = (size_t)(t) * 4096;                           \
        rKh[0] = *(const bf16x8*)(khp + toff);                            \
        rKh[1] = *(const bf16x8*)(khp + toff + 2048);                     \
        rKl[0] = *(const bf16x8*)(klp + toff);                            \
        rKl[1] = *(const bf16x8*)(klp + toff + 2048);                     \
        rVt[0] = *(const bf16x8*)(vtp + toff);                            \
        rVt[1] = *(const bf16x8*)(vtp + toff + 2048);                     \
    }

#define WRITET()                                                          \
    {                                                                     \
        _Pragma("unroll")                                                 \
        for (int j = 0; j < 2; ++j) {                                     \
            int i = tid + j * 256;                                        \
            *(bf16x8*)&Kh[(i >> 4) * PK + (i & 15) * 8] = rKh[j];         \
            *(bf16x8*)&Kl[(i >> 4) * PK + (i & 15) * 8] = rKl[j];         \
            *(bf16x8*)&Vs[i * 8] = rVt[j];                                \
        }                                                                 \
    }

    // prologue: tile 0 -> LDS, tile 1 in flight
    LOADT(0);
    WRITET();
    LOADT(1);
    __syncthreads();

    for (int it = 0; it < NIT; ++it) {
        // ---- QK^T: S[16 x 32] per wave, split-bf16 ----
        f32x4 sacc[2];
        sacc[0] = (f32x4){0.f, 0.f, 0.f, 0.f};
        sacc[1] = (f32x4){0.f, 0.f, 0.f, 0.f};
        __builtin_amdgcn_s_setprio(1);
#pragma unroll
        for (int ks = 0; ks < 4; ++ks) {
#pragma unroll
            for (int nb = 0; nb < 2; ++nb) {
                int off = (nb * 16 + l16) * PK + ks * 32 + quad * 8;
                bf16x8 kh = *(const bf16x8*)&Kh[off];
                bf16x8 kl = *(const bf16x8*)&Kl[off];
                sacc[nb] = __builtin_amdgcn_mfma_f32_16x16x32_bf16(qh[ks], kh, sacc[nb], 0, 0, 0);
                sacc[nb] = __builtin_amdgcn_mfma_f32_16x16x32_bf16(qh[ks], kl, sacc[nb], 0, 0, 0);
                sacc[nb] = __builtin_amdgcn_mfma_f32_16x16x32_bf16(ql[ks], kh, sacc[nb], 0, 0, 0);
            }
        }
        __builtin_amdgcn_s_setprio(0);

        // ---- online softmax (exp2 domain, defer-max THR=8) ----
        // Row-max reduce over the 16 l16-lanes = one DPP row: VALU DPP
        // butterfly, no LDS-pipe traffic.
        float m0r[4];
        bool grow = false;
#pragma unroll
        for (int r = 0; r < 4; ++r) {
            float m0 = row16_max(fmaxf(sacc[0][r], sacc[1][r]));
            m0r[r] = m0;
            grow |= (m0 - mrow[r] > 8.0f);
        }
        if (__any(grow)) {
            // full rescale path (rare after the first few tiles)
#pragma unroll
            for (int r = 0; r < 4; ++r) {
                float mnew  = fmaxf(mrow[r], m0r[r]);
                float alpha = __builtin_amdgcn_exp2f(mrow[r] - mnew);
                mrow[r] = mnew;
                Lp[r] *= alpha;
#pragma unroll
                for (int d = 0; d < 8; ++d) O[d][r] *= alpha;
            }
        }
        float p0[4], p1[4];
#pragma unroll
        for (int r = 0; r < 4; ++r) {
            float e0 = __builtin_amdgcn_exp2f(sacc[0][r] - mrow[r]);
            float e1 = __builtin_amdgcn_exp2f(sacc[1][r] - mrow[r]);
            p0[r] = e0; p1[r] = e1;
            Lp[r] += e0 + e1;            // per-lane partial (2 cols)
        }

        // ---- P: C-layout regs -> wave-private LDS (A-layout read below) ----
        bf16* pw = &Ps[wave * 16 * PP];
#pragma unroll
        for (int r = 0; r < 4; ++r) {
            pw[(quad * 4 + r) * PP + l16]      = (bf16)p0[r];
            pw[(quad * 4 + r) * PP + 16 + l16] = (bf16)p1[r];
        }
        // same-wave DS RAW ordered via lgkmcnt by compiler

        // ---- PV: O[16 x 128] += P[16 x 32] * V[32 x 128] ----
        {
            bf16x8 pa = *(const bf16x8*)&pw[l16 * PP + quad * 8];
            __builtin_amdgcn_s_setprio(1);
#pragma unroll
            for (int d = 0; d < 8; ++d) {
                bf16x8 vb = *(const bf16x8*)&Vs[(d * 16 + l16) * PVT + quad * 8];
                O[d] = __builtin_amdgcn_mfma_f32_16x16x32_bf16(pa, vb, O[d], 0, 0, 0);
            }
            __builtin_amdgcn_s_setprio(0);
        }

        if (it == NIT - 1) break;
        __syncthreads();            // all readers done with current tile
        WRITET();                   // stage tile it+1 (regs loaded last iter)
        if (it + 2 < NIT) LOADT(it + 2);   // in flight across next compute
        __syncthreads();            // tile it+1 visible
    }

    // ---- finalize: DPP-sum per-lane L over the 16 l16-lanes, then store ----
    float rl[4];
#pragma unroll
    for (int r = 0; r < 4; ++r)
        rl[r] = 1.0f / row16_sum(Lp[r]);
    float* og = out + ((size_t)bh * S_ + (size_t)qt * BM + wave * 16) * D_;
#pragma unroll
    for (int d = 0; d < 8; ++d)
#pragma unroll
        for (int r = 0; r < 4; ++r)
            og[(quad * 4 + r) * D_ + d * 16 + l16] = O[d][r] * rl[r];
}

// ---- fallback: round-0 verified kernel (used if ws too small) ----
__global__ __launch_bounds__(256, 4) void attn_fwd_fb(
    const float* __restrict__ q, const float* __restrict__ kg,
    const float* __restrict__ vg, const float* __restrict__ sc,
    float* __restrict__ out)
{
    constexpr int FPVT = BN + 8;  // 40

    __shared__ __align__(16) bf16 Kh[BN * PK];
    __shared__ __align__(16) bf16 Kl[BN * PK];
    __shared__ __align__(16) bf16 Vs[D_ * FPVT];
    __shared__ __align__(16) bf16 Ps2[4 * 16 * PP];

    const int tid  = threadIdx.x;
    const int wave = tid >> 6;
    const int lane = tid & 63;
    const int l16  = lane & 15;
    const int quad = lane >> 4;

    const int qt = blockIdx.x;
    const int bh = blockIdx.y;

    const float scale = sc[bh] * 1.44269504088896f;

    const float* qbase = q  + ((size_t)bh * S_ + (size_t)qt * BM) * D_;
    const float* kbase = kg + (size_t)bh * S_ * D_;
    const float* vbase = vg + (size_t)bh * S_ * D_;

    bf16x8 qh[4], ql[4];
    {
        const float* qrow = qbase + (size_t)(wave * 16 + l16) * D_ + quad * 8;
#pragma unroll
        for (int ks = 0; ks < 4; ++ks) {
            float x[8];
            *(float4*)&x[0] = *(const float4*)(qrow + ks * 32);
            *(float4*)&x[4] = *(const float4*)(qrow + ks * 32 + 4);
#pragma unroll
            for (int j = 0; j < 8; ++j) {
                float xs = x[j] * scale;
                bf16 h = (bf16)xs;
                qh[ks][j] = h;
                ql[ks][j] = (bf16)(xs - (float)h);
            }
        }
    }

    f32x4 O[8];
#pragma unroll
    for (int i = 0; i < 8; ++i) O[i] = (f32x4){0.f, 0.f, 0.f, 0.f};
    float mrow[4] = {-1e30f, -1e30f, -1e30f, -1e30f};
    float Lp[4]   = {0.f, 0.f, 0.f, 0.f};

    for (int it = 0; it < NIT; ++it) {
        __syncthreads();
        {
            const float* kt = kbase + (size_t)it * BN * D_;
#pragma unroll
            for (int r = 0; r < 4; ++r) {
                int i = tid + r * 256;
                int row = i >> 5, c = i & 31;
                float4 v = *(const float4*)(kt + row * D_ + c * 4);
                const float* x = (const float*)&v;
                bf16x4 h4, l4;
#pragma unroll
                for (int j = 0; j < 4; ++j) {
                    bf16 h = (bf16)x[j];
                    h4[j] = h;
                    l4[j] = (bf16)(x[j] - (float)h);
                }
                *(bf16x4*)&Kh[row * PK + c * 4] = h4;
                *(bf16x4*)&Kl[row * PK + c * 4] = l4;
            }
            const float* vt = vbase + (size_t)it * BN * D_;
#pragma unroll
            for (int r = 0; r < 2; ++r) {
                int i = tid + r * 256;
                int p = i & 15;
                int c = i >> 4;
                const float* v0 = vt + (2 * p) * D_ + c * 4;
                float4 a0 = *(const float4*)v0;
                float4 a1 = *(const float4*)(v0 + D_);
                const float* x0 = (const float*)&a0;
                const float* x1 = (const float*)&a1;
#pragma unroll
                for (int j = 0; j < 4; ++j) {
                    union { ushort2 u; bf16 b[2]; } pr;
                    pr.b[0] = (bf16)x0[j];
                    pr.b[1] = (bf16)x1[j];
                    *(ushort2*)&Vs[(c * 4 + j) * FPVT + 2 * p] = pr.u;
                }
            }
        }
        __syncthreads();

        f32x4 sacc[2];
        sacc[0] = (f32x4){0.f, 0.f, 0.f, 0.f};
        sacc[1] = (f32x4){0.f, 0.f, 0.f, 0.f};
#pragma unroll
        for (int ks = 0; ks < 4; ++ks) {
#pragma unroll
            for (int nb = 0; nb < 2; ++nb) {
                int off = (nb * 16 + l16) * PK + ks * 32 + quad * 8;
                bf16x8 kh = *(const bf16x8*)&Kh[off];
                bf16x8 kl = *(const bf16x8*)&Kl[off];
                sacc[nb] = __builtin_amdgcn_mfma_f32_16x16x32_bf16(qh[ks], kh, sacc[nb], 0, 0, 0);
                sacc[nb] = __builtin_amdgcn_mfma_f32_16x16x32_bf16(qh[ks], kl, sacc[nb], 0, 0, 0);
                sacc[nb] = __builtin_amdgcn_mfma_f32_16x16x32_bf16(ql[ks], kh, sacc[nb], 0, 0, 0);
            }
        }

        float p0[4], p1[4];
#pragma unroll
        for (int r = 0; r < 4; ++r) {
            float m0 = fmaxf(sacc[0][r], sacc[1][r]);
#pragma unroll
            for (int off = 8; off >= 1; off >>= 1)
                m0 = fmaxf(m0, __shfl_xor(m0, off, 64));
            float mnew  = fmaxf(mrow[r], m0);
            float alpha = __builtin_amdgcn_exp2f(mrow[r] - mnew);
            mrow[r] = mnew;
            float e0 = __builtin_amdgcn_exp2f(sacc[0][r] - mnew);
            float e1 = __builtin_amdgcn_exp2f(sacc[1][r] - mnew);
            p0[r] = e0; p1[r] = e1;
            Lp[r] = Lp[r] * alpha + (e0 + e1);
#pragma unroll
            for (int d = 0; d < 8; ++d) O[d][r] *= alpha;
        }

        bf16* pw = &Ps2[wave * 16 * PP];
#pragma unroll
        for (int r = 0; r < 4; ++r) {
            pw[(quad * 4 + r) * PP + l16]      = (bf16)p0[r];
            pw[(quad * 4 + r) * PP + 16 + l16] = (bf16)p1[r];
        }
        {
            bf16x8 pa = *(const bf16x8*)&pw[l16 * PP + quad * 8];
#pragma unroll
            for (int d = 0; d < 8; ++d) {
                bf16x8 vb = *(const bf16x8*)&Vs[(d * 16 + l16) * FPVT + quad * 8];
                O[d] = __builtin_amdgcn_mfma_f32_16x16x32_bf16(pa, vb, O[d], 0, 0, 0);
            }
        }
    }

    float rl[4];
#pragma unroll
    for (int r = 0; r < 4; ++r) {
        float L = Lp[r];
#pragma unroll
        for (int off = 8; off >= 1; off >>= 1)
            L += __shfl_xor(L, off, 64);
        rl[r] = 1.0f / L;
    }
    float* og = out + ((size_t)bh * S_ + (size_t)qt * BM + wave * 16) * D_;
#pragma unroll
    for (int d = 0; d < 8; ++d)
#pragma unroll
        for (int r = 0; r < 4; ++r)
            og[(quad * 4 + r) * D_ + d * 16 + l16] = O[d][r] * rl[r];
}

extern "C" void kernel_launch(void* const* d_in, const int* in_sizes, int n_in,
                              void* d_out, int out_size, void* d_ws, size_t ws_size,
                              hipStream_t stream) {
    const float* q  = (const float*)d_in[0];
    const float* k  = (const float*)d_in[1];
    const float* v  = (const float*)d_in[2];
    const float* sc = (const float*)d_in[3];
    float* o = (float*)d_out;
    if (d_ws && ws_size >= WS_NEED) {
        bf16* ws = (bf16*)d_ws;
        prepack<<<16384, 256, 0, stream>>>(k, v, ws);          // ~60 us
        attn_fwd<<<2048, 256, 0, stream>>>(q, ws, sc, o);
    } else {
        attn_fwd_fb<<<dim3(S_ / BM, 64), 256, 0, stream>>>(q, k, v, sc, o);
    }
}

// Round 6
// 524.772 us; speedup vs baseline: 3.0958x; 3.0958x over previous
//
#include <hip/hip_runtime.h>
#include <hip/hip_bf16.h>

// Flash attention fwd, B=4 H=16 S=2048 D=128. fp32 in/out.
// Round-9: round-8 content (DPP softmax reduce off the LDS pipe, Vs pitch 32,
// 30720 B LDS) with the launch bound reverted to (256,4). Round-8's (256,5)
// capped the unified reg budget at ~102 and the VGPR split landed at 48 ->
// massive scratch spills (WRITE_SIZE 3.17 GB, 1504us). With (256,4) the
// compiler allocates ~64 VGPR (round-4 measured), which still PERMITS
// 5 blocks/CU at 30720 B LDS - occupancy is earned by usage, not forced by
// the bound. LESSON (2x burned): never force min-waves > 4 on this kernel.
// Everything else identical to the verified 483us round-7 kernel: prepacked
// bf16 K hi/lo + V^T in d_ws, reg-prefetch staging, split-bf16 QK^T,
// exp2-domain defer-max online softmax (THR=8), setprio around MFMA,
// head-affinity XCD swizzle.

typedef __bf16 bf16;
typedef __attribute__((ext_vector_type(4))) __bf16 bf16x4;
typedef __attribute__((ext_vector_type(8))) __bf16 bf16x8;
typedef __attribute__((ext_vector_type(4))) float f32x4;

constexpr int S_  = 2048;
constexpr int D_  = 128;
constexpr int BM  = 64;       // Q rows per block (4 waves x 16)
constexpr int BN  = 32;       // K/V rows per tile
constexpr int NIT = S_ / BN;  // 64
constexpr int PK  = D_ + 8;   // 136 bf16 K pitch (balanced bank groups)
constexpr int PVT = 32;       // V^T pitch (balanced: 8 lanes/4-bank group)
constexpr int PP  = BN + 8;   // 40 bf16 P pitch

// bf16-element offsets of the packed images inside d_ws
constexpr size_t WS_KL   = 16777216;   // Klo image at +32 MB
constexpr size_t WS_VT   = 33554432;   // V^T image at +64 MB
constexpr size_t WS_NEED = 100663296;  // 96 MB total (bytes)

// ---- DPP 16-lane (one DPP row) reductions, zero LDS-pipe traffic ----
template <int CTRL>
__device__ __forceinline__ float dpp_fmax_step(float x) {
    int yi = __builtin_amdgcn_update_dpp(
        __float_as_int(x), __float_as_int(x), CTRL, 0xf, 0xf, false);
    return fmaxf(x, __int_as_float(yi));
}
template <int CTRL>
__device__ __forceinline__ float dpp_fadd_step(float x) {
    int yi = __builtin_amdgcn_update_dpp(
        __float_as_int(x), __float_as_int(x), CTRL, 0xf, 0xf, false);
    return x + __int_as_float(yi);
}
__device__ __forceinline__ float row16_max(float x) {
    x = dpp_fmax_step<0xB1>(x);   // quad_perm [1,0,3,2]  (lane^1)
    x = dpp_fmax_step<0x4E>(x);   // quad_perm [2,3,0,1]  (lane^2)
    x = dpp_fmax_step<0x141>(x);  // row_half_mirror      (combine 4s -> 8)
    x = dpp_fmax_step<0x140>(x);  // row_mirror           (combine 8s -> 16)
    return x;
}
__device__ __forceinline__ float row16_sum(float x) {
    x = dpp_fadd_step<0xB1>(x);
    x = dpp_fadd_step<0x4E>(x);
    x = dpp_fadd_step<0x141>(x);
    x = dpp_fadd_step<0x140>(x);
    return x;
}

// ---- pre-pack ----
// Kh/Kl images: [head][s][d] bf16, pitch 128 (tile it = 4096-elem block).
// V^T image: [head][tile][d][32] bf16 (per (head,tile) 4096 elems).
__global__ __launch_bounds__(256) void prepack(
    const float* __restrict__ kg, const float* __restrict__ vg,
    bf16* __restrict__ ws)
{
    const int gid = blockIdx.x * 256 + threadIdx.x;
    if (gid < 2097152) {                  // K: (64*2048 rows) x 16 chunks
        const int u  = gid & 15;
        const int rg = gid >> 4;          // head*2048 + s
        const float* src = kg + (size_t)rg * D_ + (u << 3);
        float x[8];
        *(float4*)&x[0] = *(const float4*)src;
        *(float4*)&x[4] = *(const float4*)(src + 4);
        bf16x8 h8, l8;
#pragma unroll
        for (int j = 0; j < 8; ++j) {
            bf16 h = (bf16)x[j];
            h8[j] = h;
            l8[j] = (bf16)(x[j] - (float)h);
        }
        const size_t di = (size_t)rg * 128 + (u << 3);
        *(bf16x8*)&ws[di]         = h8;
        *(bf16x8*)&ws[WS_KL + di] = l8;
    } else {                              // V: 4096 (head,tile) x 512 tasks
        const int g2 = gid - 2097152;
        const int i  = g2 & 511;
        const int tg = g2 >> 9;           // head*64 + tile
        const int p  = i & 15;            // t-pair: rows 2p, 2p+1
        const int c  = i >> 4;            // 0..31: cols 4c..4c+3
        const float* src = vg + ((size_t)tg * BN + 2 * p) * D_ + c * 4;
        float4 a0 = *(const float4*)src;
        float4 a1 = *(const float4*)(src + D_);
        const float* x0 = (const float*)&a0;
        const float* x1 = (const float*)&a1;
        bf16* vt = ws + WS_VT + (size_t)tg * 4096;
#pragma unroll
        for (int j = 0; j < 4; ++j) {
            union { ushort2 u2; bf16 b[2]; } pr;
            pr.b[0] = (bf16)x0[j];
            pr.b[1] = (bf16)x1[j];
            *(ushort2*)&vt[(c * 4 + j) * BN + 2 * p] = pr.u2;
        }
    }
}

// ---- main kernel: 4 waves x 16 Q-rows, 30 KB LDS ----
__global__ __launch_bounds__(256, 4) void attn_fwd(
    const float* __restrict__ q, const bf16* __restrict__ ws,
    const float* __restrict__ sc, float* __restrict__ out)
{
    __shared__ __align__(16) bf16 Kh[BN * PK];      // 8704 B
    __shared__ __align__(16) bf16 Kl[BN * PK];      // 8704 B
    __shared__ __align__(16) bf16 Vs[D_ * PVT];     // 8192 B (Vs[d][t])
    __shared__ __align__(16) bf16 Ps[4 * 16 * PP];  // 5120 B (wave-private)
    // total 30720 B; at 64 VGPR the HW can fit 5 blocks/CU

    const int tid  = threadIdx.x;
    const int wave = tid >> 6;
    const int lane = tid & 63;
    const int l16  = lane & 15;
    const int quad = lane >> 4;

    // head-affinity XCD swizzle: 2048 blocks; XCD (bid&7) gets heads 8x..8x+7
    const int bid = blockIdx.x;
    const int idx = bid >> 3;                        // 0..255
    const int bh  = ((bid & 7) << 3) | (idx >> 5);   // head 0..63
    const int qt  = idx & 31;                        // Q tile 0..31

    const float scale = sc[bh] * 1.44269504088896f;  // fold log2(e)

    const float* qbase = q + ((size_t)bh * S_ + (size_t)qt * BM) * D_;
    const bf16* khp = ws +         (size_t)bh * 262144 + tid * 8;
    const bf16* klp = ws + WS_KL + (size_t)bh * 262144 + tid * 8;
    const bf16* vtp = ws + WS_VT + (size_t)bh * 262144 + tid * 8;

    // Q fragments (A-layout: m=l16, k=quad*8+j, +32*ks), scale folded, hi/lo
    bf16x8 qh[4], ql[4];
    {
        const float* qrow = qbase + (size_t)(wave * 16 + l16) * D_ + quad * 8;
#pragma unroll
        for (int ks = 0; ks < 4; ++ks) {
            float x[8];
            *(float4*)&x[0] = *(const float4*)(qrow + ks * 32);
            *(float4*)&x[4] = *(const float4*)(qrow + ks * 32 + 4);
#pragma unroll
            for (int j = 0; j < 8; ++j) {
                float xs = x[j] * scale;
                bf16 h = (bf16)xs;
                qh[ks][j] = h;
                ql[ks][j] = (bf16)(xs - (float)h);
            }
        }
    }

    f32x4 O[8];                  // O[dblk][r]: row=quad*4+r, col=l16+16*dblk
#pragma unroll
    for (int i = 0; i < 8; ++i) O[i] = (f32x4){0.f, 0.f, 0.f, 0.f};
    float mrow[4] = {-1e30f, -1e30f, -1e30f, -1e30f};
    float Lp[4]   = {0.f, 0.f, 0.f, 0.f};   // per-lane partial row sums

    // prefetch registers: 6 x 16 B held across one full compute phase
    bf16x8 rKh[2], rKl[2], rVt[2];

#define LOADT(t)                                                          \
    {                                                                     \
        const size_t toff = (size_t)(t) * 4096;                           \
        rKh[0] = *(const bf16x8*)(khp + toff);                            \
        rKh[1] = *(const bf16x8*)(khp + toff + 2048);                     \
        rKl[0] = *(const bf16x8*)(klp + toff);                            \
        rKl[1] = *(const bf16x8*)(klp + toff + 2048);                     \
        rVt[0] = *(const bf16x8*)(vtp + toff);                            \
        rVt[1] = *(const bf16x8*)(vtp + toff + 2048);                     \
    }

#define WRITET()                                                          \
    {                                                                     \
        _Pragma("unroll")                                                 \
        for (int j = 0; j < 2; ++j) {                                     \
            int i = tid + j * 256;                                        \
            *(bf16x8*)&Kh[(i >> 4) * PK + (i & 15) * 8] = rKh[j];         \
            *(bf16x8*)&Kl[(i >> 4) * PK + (i & 15) * 8] = rKl[j];         \
            *(bf16x8*)&Vs[i * 8] = rVt[j];                                \
        }                                                                 \
    }

    // prologue: tile 0 -> LDS, tile 1 in flight
    LOADT(0);
    WRITET();
    LOADT(1);
    __syncthreads();

    for (int it = 0; it < NIT; ++it) {
        // ---- QK^T: S[16 x 32] per wave, split-bf16 ----
        f32x4 sacc[2];
        sacc[0] = (f32x4){0.f, 0.f, 0.f, 0.f};
        sacc[1] = (f32x4){0.f, 0.f, 0.f, 0.f};
        __builtin_amdgcn_s_setprio(1);
#pragma unroll
        for (int ks = 0; ks < 4; ++ks) {
#pragma unroll
            for (int nb = 0; nb < 2; ++nb) {
                int off = (nb * 16 + l16) * PK + ks * 32 + quad * 8;
                bf16x8 kh = *(const bf16x8*)&Kh[off];
                bf16x8 kl = *(const bf16x8*)&Kl[off];
                sacc[nb] = __builtin_amdgcn_mfma_f32_16x16x32_bf16(qh[ks], kh, sacc[nb], 0, 0, 0);
                sacc[nb] = __builtin_amdgcn_mfma_f32_16x16x32_bf16(qh[ks], kl, sacc[nb], 0, 0, 0);
                sacc[nb] = __builtin_amdgcn_mfma_f32_16x16x32_bf16(ql[ks], kh, sacc[nb], 0, 0, 0);
            }
        }
        __builtin_amdgcn_s_setprio(0);

        // ---- online softmax (exp2 domain, defer-max THR=8) ----
        // Row-max reduce over the 16 l16-lanes = one DPP row: VALU DPP
        // butterfly, no LDS-pipe traffic.
        float m0r[4];
        bool grow = false;
#pragma unroll
        for (int r = 0; r < 4; ++r) {
            float m0 = row16_max(fmaxf(sacc[0][r], sacc[1][r]));
            m0r[r] = m0;
            grow |= (m0 - mrow[r] > 8.0f);
        }
        if (__any(grow)) {
            // full rescale path (rare after the first few tiles)
#pragma unroll
            for (int r = 0; r < 4; ++r) {
                float mnew  = fmaxf(mrow[r], m0r[r]);
                float alpha = __builtin_amdgcn_exp2f(mrow[r] - mnew);
                mrow[r] = mnew;
                Lp[r] *= alpha;
#pragma unroll
                for (int d = 0; d < 8; ++d) O[d][r] *= alpha;
            }
        }
        float p0[4], p1[4];
#pragma unroll
        for (int r = 0; r < 4; ++r) {
            float e0 = __builtin_amdgcn_exp2f(sacc[0][r] - mrow[r]);
            float e1 = __builtin_amdgcn_exp2f(sacc[1][r] - mrow[r]);
            p0[r] = e0; p1[r] = e1;
            Lp[r] += e0 + e1;            // per-lane partial (2 cols)
        }

        // ---- P: C-layout regs -> wave-private LDS (A-layout read below) ----
        bf16* pw = &Ps[wave * 16 * PP];
#pragma unroll
        for (int r = 0; r < 4; ++r) {
            pw[(quad * 4 + r) * PP + l16]      = (bf16)p0[r];
            pw[(quad * 4 + r) * PP + 16 + l16] = (bf16)p1[r];
        }
        // same-wave DS RAW ordered via lgkmcnt by compiler

        // ---- PV: O[16 x 128] += P[16 x 32] * V[32 x 128] ----
        {
            bf16x8 pa = *(const bf16x8*)&pw[l16 * PP + quad * 8];
            __builtin_amdgcn_s_setprio(1);
#pragma unroll
            for (int d = 0; d < 8; ++d) {
                bf16x8 vb = *(const bf16x8*)&Vs[(d * 16 + l16) * PVT + quad * 8];
                O[d] = __builtin_amdgcn_mfma_f32_16x16x32_bf16(pa, vb, O[d], 0, 0, 0);
            }
            __builtin_amdgcn_s_setprio(0);
        }

        if (it == NIT - 1) break;
        __syncthreads();            // all readers done with current tile
        WRITET();                   // stage tile it+1 (regs loaded last iter)
        if (it + 2 < NIT) LOADT(it + 2);   // in flight across next compute
        __syncthreads();            // tile it+1 visible
    }

    // ---- finalize: DPP-sum per-lane L over the 16 l16-lanes, then store ----
    float rl[4];
#pragma unroll
    for (int r = 0; r < 4; ++r)
        rl[r] = 1.0f / row16_sum(Lp[r]);
    float* og = out + ((size_t)bh * S_ + (size_t)qt * BM + wave * 16) * D_;
#pragma unroll
    for (int d = 0; d < 8; ++d)
#pragma unroll
        for (int r = 0; r < 4; ++r)
            og[(quad * 4 + r) * D_ + d * 16 + l16] = O[d][r] * rl[r];
}

// ---- fallback: round-0 verified kernel (used if ws too small) ----
__global__ __launch_bounds__(256, 4) void attn_fwd_fb(
    const float* __restrict__ q, const float* __restrict__ kg,
    const float* __restrict__ vg, const float* __restrict__ sc,
    float* __restrict__ out)
{
    constexpr int FPVT = BN + 8;  // 40

    __shared__ __align__(16) bf16 Kh[BN * PK];
    __shared__ __align__(16) bf16 Kl[BN * PK];
    __shared__ __align__(16) bf16 Vs[D_ * FPVT];
    __shared__ __align__(16) bf16 Ps2[4 * 16 * PP];

    const int tid  = threadIdx.x;
    const int wave = tid >> 6;
    const int lane = tid & 63;
    const int l16  = lane & 15;
    const int quad = lane >> 4;

    const int qt = blockIdx.x;
    const int bh = blockIdx.y;

    const float scale = sc[bh] * 1.44269504088896f;

    const float* qbase = q  + ((size_t)bh * S_ + (size_t)qt * BM) * D_;
    const float* kbase = kg + (size_t)bh * S_ * D_;
    const float* vbase = vg + (size_t)bh * S_ * D_;

    bf16x8 qh[4], ql[4];
    {
        const float* qrow = qbase + (size_t)(wave * 16 + l16) * D_ + quad * 8;
#pragma unroll
        for (int ks = 0; ks < 4; ++ks) {
            float x[8];
            *(float4*)&x[0] = *(const float4*)(qrow + ks * 32);
            *(float4*)&x[4] = *(const float4*)(qrow + ks * 32 + 4);
#pragma unroll
            for (int j = 0; j < 8; ++j) {
                float xs = x[j] * scale;
                bf16 h = (bf16)xs;
                qh[ks][j] = h;
                ql[ks][j] = (bf16)(xs - (float)h);
            }
        }
    }

    f32x4 O[8];
#pragma unroll
    for (int i = 0; i < 8; ++i) O[i] = (f32x4){0.f, 0.f, 0.f, 0.f};
    float mrow[4] = {-1e30f, -1e30f, -1e30f, -1e30f};
    float Lp[4]   = {0.f, 0.f, 0.f, 0.f};

    for (int it = 0; it < NIT; ++it) {
        __syncthreads();
        {
            const float* kt = kbase + (size_t)it * BN * D_;
#pragma unroll
            for (int r = 0; r < 4; ++r) {
                int i = tid + r * 256;
                int row = i >> 5, c = i & 31;
                float4 v = *(const float4*)(kt + row * D_ + c * 4);
                const float* x = (const float*)&v;
                bf16x4 h4, l4;
#pragma unroll
                for (int j = 0; j < 4; ++j) {
                    bf16 h = (bf16)x[j];
                    h4[j] = h;
                    l4[j] = (bf16)(x[j] - (float)h);
                }
                *(bf16x4*)&Kh[row * PK + c * 4] = h4;
                *(bf16x4*)&Kl[row * PK + c * 4] = l4;
            }
            const float* vt = vbase + (size_t)it * BN * D_;
#pragma unroll
            for (int r = 0; r < 2; ++r) {
                int i = tid + r * 256;
                int p = i & 15;
                int c = i >> 4;
                const float* v0 = vt + (2 * p) * D_ + c * 4;
                float4 a0 = *(const float4*)v0;
                float4 a1 = *(const float4*)(v0 + D_);
                const float* x0 = (const float*)&a0;
                const float* x1 = (const float*)&a1;
#pragma unroll
                for (int j = 0; j < 4; ++j) {
                    union { ushort2 u; bf16 b[2]; } pr;
                    pr.b[0] = (bf16)x0[j];
                    pr.b[1] = (bf16)x1[j];
                    *(ushort2*)&Vs[(c * 4 + j) * FPVT + 2 * p] = pr.u;
                }
            }
        }
        __syncthreads();

        f32x4 sacc[2];
        sacc[0] = (f32x4){0.f, 0.f, 0.f, 0.f};
        sacc[1] = (f32x4){0.f, 0.f, 0.f, 0.f};
#pragma unroll
        for (int ks = 0; ks < 4; ++ks) {
#pragma unroll
            for (int nb = 0; nb < 2; ++nb) {
                int off = (nb * 16 + l16) * PK + ks * 32 + quad * 8;
                bf16x8 kh = *(const bf16x8*)&Kh[off];
                bf16x8 kl = *(const bf16x8*)&Kl[off];
                sacc[nb] = __builtin_amdgcn_mfma_f32_16x16x32_bf16(qh[ks], kh, sacc[nb], 0, 0, 0);
                sacc[nb] = __builtin_amdgcn_mfma_f32_16x16x32_bf16(qh[ks], kl, sacc[nb], 0, 0, 0);
                sacc[nb] = __builtin_amdgcn_mfma_f32_16x16x32_bf16(ql[ks], kh, sacc[nb], 0, 0, 0);
            }
        }

        float p0[4], p1[4];
#pragma unroll
        for (int r = 0; r < 4; ++r) {
            float m0 = fmaxf(sacc[0][r], sacc[1][r]);
#pragma unroll
            for (int off = 8; off >= 1; off >>= 1)
                m0 = fmaxf(m0, __shfl_xor(m0, off, 64));
            float mnew  = fmaxf(mrow[r], m0);
            float alpha = __builtin_amdgcn_exp2f(mrow[r] - mnew);
            mrow[r] = mnew;
            float e0 = __builtin_amdgcn_exp2f(sacc[0][r] - mnew);
            float e1 = __builtin_amdgcn_exp2f(sacc[1][r] - mnew);
            p0[r] = e0; p1[r] = e1;
            Lp[r] = Lp[r] * alpha + (e0 + e1);
#pragma unroll
            for (int d = 0; d < 8; ++d) O[d][r] *= alpha;
        }

        bf16* pw = &Ps2[wave * 16 * PP];
#pragma unroll
        for (int r = 0; r < 4; ++r) {
            pw[(quad * 4 + r) * PP + l16]      = (bf16)p0[r];
            pw[(quad * 4 + r) * PP + 16 + l16] = (bf16)p1[r];
        }
        {
            bf16x8 pa = *(const bf16x8*)&pw[l16 * PP + quad * 8];
#pragma unroll
            for (int d = 0; d < 8; ++d) {
                bf16x8 vb = *(const bf16x8*)&Vs[(d * 16 + l16) * FPVT + quad * 8];
                O[d] = __builtin_amdgcn_mfma_f32_16x16x32_bf16(pa, vb, O[d], 0, 0, 0);
            }
        }
    }

    float rl[4];
#pragma unroll
    for (int r = 0; r < 4; ++r) {
        float L = Lp[r];
#pragma unroll
        for (int off = 8; off >= 1; off >>= 1)
            L += __shfl_xor(L, off, 64);
        rl[r] = 1.0f / L;
    }
    float* og = out + ((size_t)bh * S_ + (size_t)qt * BM + wave * 16) * D_;
#pragma unroll
    for (int d = 0; d < 8; ++d)
#pragma unroll
        for (int r = 0; r < 4; ++r)
            og[(quad * 4 + r) * D_ + d * 16 + l16] = O[d][r] * rl[r];
}

extern "C" void kernel_launch(void* const* d_in, const int* in_sizes, int n_in,
                              void* d_out, int out_size, void* d_ws, size_t ws_size,
                              hipStream_t stream) {
    const float* q  = (const float*)d_in[0];
    const float* k  = (const float*)d_in[1];
    const float* v  = (const float*)d_in[2];
    const float* sc = (const float*)d_in[3];
    float* o = (float*)d_out;
    if (d_ws && ws_size >= WS_NEED) {
        bf16* ws = (bf16*)d_ws;
        prepack<<<16384, 256, 0, stream>>>(k, v, ws);          // ~60 us
        attn_fwd<<<2048, 256, 0, stream>>>(q, ws, sc, o);
    } else {
        attn_fwd_fb<<<dim3(S_ / BM, 64), 256, 0, stream>>>(q, k, v, sc, o);
    }
}

// Round 8
// 523.984 us; speedup vs baseline: 3.1004x; 1.0015x over previous
//
#include <hip/hip_runtime.h>
#include <hip/hip_bf16.h>

// Flash attention fwd, B=4 H=16 S=2048 D=128. fp32 in/out.
// Round-10 (resubmit; round-7 bench was an infra failure - container died,
// kernel never ran): 32 Q-rows per wave (BM=128, 4 waves x 32 rows, grid
// 1024). At 372us the kernel was ~87% LDS-pipe bound and the dominant term
// was the 16 K-tile b128 reads/wave-iter serving only 16 Q-rows. Now each
// kh/kl read pair feeds 6 MFMAs (2 m-blocks x 3 split terms) and each V
// read feeds 2 PV MFMAs: DS ops per Q-row drop 2.44 -> 1.5 (-39%); staging
// per work halves. PVT back to 40 (PVT=32's PV read phase was
// bank-unbalanced: (4*l16+quad)&7 hits {0,4} for lanes 0-7; pitch 40 =
// (5*l16+quad)&7 is a perfect 8-group permutation).
// Registers: ~220 peak -> __launch_bounds__(256,2) (cap 256, headroom; the
// r3/r5 spill disasters were caps BELOW need - never force min-waves so the
// cap dips under live state). 2 blocks/CU; per-wave ILP (64 MFMAs/iter)
// carries latency hiding.
// Kept: prepacked bf16 K hi/lo + V^T in d_ws, reg-prefetch staging,
// split-bf16 QK^T, exp2-domain defer-max softmax (THR=8), DPP row16
// reductions, setprio on MFMA clusters, head-affinity XCD swizzle.

typedef __bf16 bf16;
typedef __attribute__((ext_vector_type(4))) __bf16 bf16x4;
typedef __attribute__((ext_vector_type(8))) __bf16 bf16x8;
typedef __attribute__((ext_vector_type(4))) float f32x4;

constexpr int S_  = 2048;
constexpr int D_  = 128;
constexpr int BM  = 128;      // Q rows per block (4 waves x 32)
constexpr int BN  = 32;       // K/V rows per tile
constexpr int NIT = S_ / BN;  // 64
constexpr int PK  = D_ + 8;   // 136 bf16 K pitch (balanced bank groups)
constexpr int PVT = BN + 8;   // 40 bf16 V^T pitch (balanced bank groups)
constexpr int PP  = BN + 8;   // 40 bf16 P pitch

// bf16-element offsets of the packed images inside d_ws
constexpr size_t WS_KL   = 16777216;   // Klo image at +32 MB
constexpr size_t WS_VT   = 33554432;   // V^T image at +64 MB
constexpr size_t WS_NEED = 100663296;  // 96 MB total (bytes)

// ---- DPP 16-lane (one DPP row) reductions, zero LDS-pipe traffic ----
template <int CTRL>
__device__ __forceinline__ float dpp_fmax_step(float x) {
    int yi = __builtin_amdgcn_update_dpp(
        __float_as_int(x), __float_as_int(x), CTRL, 0xf, 0xf, false);
    return fmaxf(x, __int_as_float(yi));
}
template <int CTRL>
__device__ __forceinline__ float dpp_fadd_step(float x) {
    int yi = __builtin_amdgcn_update_dpp(
        __float_as_int(x), __float_as_int(x), CTRL, 0xf, 0xf, false);
    return x + __int_as_float(yi);
}
__device__ __forceinline__ float row16_max(float x) {
    x = dpp_fmax_step<0xB1>(x);   // quad_perm [1,0,3,2]  (lane^1)
    x = dpp_fmax_step<0x4E>(x);   // quad_perm [2,3,0,1]  (lane^2)
    x = dpp_fmax_step<0x141>(x);  // row_half_mirror      (4s -> 8)
    x = dpp_fmax_step<0x140>(x);  // row_mirror           (8s -> 16)
    return x;
}
__device__ __forceinline__ float row16_sum(float x) {
    x = dpp_fadd_step<0xB1>(x);
    x = dpp_fadd_step<0x4E>(x);
    x = dpp_fadd_step<0x141>(x);
    x = dpp_fadd_step<0x140>(x);
    return x;
}

// ---- pre-pack ----
// Kh/Kl images: [head][s][d] bf16, pitch 128 (tile it = 4096-elem block).
// V^T image: [head][tile][d][32] bf16 (per (head,tile) 4096 elems).
__global__ __launch_bounds__(256) void prepack(
    const float* __restrict__ kg, const float* __restrict__ vg,
    bf16* __restrict__ ws)
{
    const int gid = blockIdx.x * 256 + threadIdx.x;
    if (gid < 2097152) {                  // K: (64*2048 rows) x 16 chunks
        const int u  = gid & 15;
        const int rg = gid >> 4;          // head*2048 + s
        const float* src = kg + (size_t)rg * D_ + (u << 3);
        float x[8];
        *(float4*)&x[0] = *(const float4*)src;
        *(float4*)&x[4] = *(const float4*)(src + 4);
        bf16x8 h8, l8;
#pragma unroll
        for (int j = 0; j < 8; ++j) {
            bf16 h = (bf16)x[j];
            h8[j] = h;
            l8[j] = (bf16)(x[j] - (float)h);
        }
        const size_t di = (size_t)rg * 128 + (u << 3);
        *(bf16x8*)&ws[di]         = h8;
        *(bf16x8*)&ws[WS_KL + di] = l8;
    } else {                              // V: 4096 (head,tile) x 512 tasks
        const int g2 = gid - 2097152;
        const int i  = g2 & 511;
        const int tg = g2 >> 9;           // head*64 + tile
        const int p  = i & 15;            // t-pair: rows 2p, 2p+1
        const int c  = i >> 4;            // 0..31: cols 4c..4c+3
        const float* src = vg + ((size_t)tg * BN + 2 * p) * D_ + c * 4;
        float4 a0 = *(const float4*)src;
        float4 a1 = *(const float4*)(src + D_);
        const float* x0 = (const float*)&a0;
        const float* x1 = (const float*)&a1;
        bf16* vt = ws + WS_VT + (size_t)tg * 4096;
#pragma unroll
        for (int j = 0; j < 4; ++j) {
            union { ushort2 u2; bf16 b[2]; } pr;
            pr.b[0] = (bf16)x0[j];
            pr.b[1] = (bf16)x1[j];
            *(ushort2*)&vt[(c * 4 + j) * BN + 2 * p] = pr.u2;
        }
    }
}

// ---- main kernel: 4 waves x 32 Q-rows, 37888 B LDS, 2 blocks/CU ----
__global__ __launch_bounds__(256, 2) void attn_fwd(
    const float* __restrict__ q, const bf16* __restrict__ ws,
    const float* __restrict__ sc, float* __restrict__ out)
{
    __shared__ __align__(16) bf16 Kh[BN * PK];      // 8704 B
    __shared__ __align__(16) bf16 Kl[BN * PK];      // 8704 B
    __shared__ __align__(16) bf16 Vs[D_ * PVT];     // 10240 B (Vs[d][t])
    __shared__ __align__(16) bf16 Ps[4 * 32 * PP];  // 10240 B (wave-private)
    // total 37888 B

    const int tid  = threadIdx.x;
    const int wave = tid >> 6;
    const int lane = tid & 63;
    const int l16  = lane & 15;
    const int quad = lane >> 4;

    // head-affinity XCD swizzle: 1024 blocks; XCD (bid&7) gets heads 8x..8x+7
    const int bid = blockIdx.x;
    const int idx = bid >> 3;                        // 0..127
    const int bh  = ((bid & 7) << 3) | (idx >> 4);   // head 0..63
    const int qt  = idx & 15;                        // Q tile 0..15 (128 rows)

    const float scale = sc[bh] * 1.44269504088896f;  // fold log2(e)

    const float* qbase = q + ((size_t)bh * S_ + (size_t)qt * BM) * D_;
    const bf16* khp = ws +         (size_t)bh * 262144 + tid * 8;
    const bf16* klp = ws + WS_KL + (size_t)bh * 262144 + tid * 8;
    const bf16* vtp = ws + WS_VT + (size_t)bh * 262144 + tid * 8;

    // Q fragments, 2 m-blocks of 16 rows (A-layout: m=l16, k=quad*8+j,+32ks)
    bf16x8 qh[2][4], ql[2][4];
#pragma unroll
    for (int mb = 0; mb < 2; ++mb) {
        const float* qrow =
            qbase + (size_t)(wave * 32 + mb * 16 + l16) * D_ + quad * 8;
#pragma unroll
        for (int ks = 0; ks < 4; ++ks) {
            float x[8];
            *(float4*)&x[0] = *(const float4*)(qrow + ks * 32);
            *(float4*)&x[4] = *(const float4*)(qrow + ks * 32 + 4);
#pragma unroll
            for (int j = 0; j < 8; ++j) {
                float xs = x[j] * scale;
                bf16 h = (bf16)xs;
                qh[mb][ks][j] = h;
                ql[mb][ks][j] = (bf16)(xs - (float)h);
            }
        }
    }

    f32x4 O[2][8];               // O[mb][dblk]: row=mb*16+quad*4+r
#pragma unroll
    for (int mb = 0; mb < 2; ++mb)
#pragma unroll
        for (int i = 0; i < 8; ++i) O[mb][i] = (f32x4){0.f, 0.f, 0.f, 0.f};
    float mrow[2][4], Lp[2][4];
#pragma unroll
    for (int mb = 0; mb < 2; ++mb)
#pragma unroll
        for (int r = 0; r < 4; ++r) { mrow[mb][r] = -1e30f; Lp[mb][r] = 0.f; }

    // prefetch registers: 6 x 16 B held across one full compute phase
    bf16x8 rKh[2], rKl[2], rVt[2];

#define LOADT(t)                                                          \
    {                                                                     \
        const size_t toff = (size_t)(t) * 4096;                           \
        rKh[0] = *(const bf16x8*)(khp + toff);                            \
        rKh[1] = *(const bf16x8*)(khp + toff + 2048);                     \
        rKl[0] = *(const bf16x8*)(klp + toff);                            \
        rKl[1] = *(const bf16x8*)(klp + toff + 2048);                     \
        rVt[0] = *(const bf16x8*)(vtp + toff);                            \
        rVt[1] = *(const bf16x8*)(vtp + toff + 2048);                     \
    }

#define WRITET()                                                          \
    {                                                                     \
        _Pragma("unroll")                                                 \
        for (int j = 0; j < 2; ++j) {                                     \
            int i = tid + j * 256;                                        \
            *(bf16x8*)&Kh[(i >> 4) * PK + (i & 15) * 8] = rKh[j];         \
            *(bf16x8*)&Kl[(i >> 4) * PK + (i & 15) * 8] = rKl[j];         \
            *(bf16x8*)&Vs[(i >> 2) * PVT + (i & 3) * 8] = rVt[j];         \
        }                                                                 \
    }

    // prologue: tile 0 -> LDS, tile 1 in flight
    LOADT(0);
    WRITET();
    LOADT(1);
    __syncthreads();

    for (int it = 0; it < NIT; ++it) {
        // ---- QK^T: S[32 x 32] per wave; kh/kl read once -> 6 MFMAs ----
        f32x4 sacc[2][2];        // [mb][nb]
#pragma unroll
        for (int mb = 0; mb < 2; ++mb)
#pragma unroll
            for (int nb = 0; nb < 2; ++nb)
                sacc[mb][nb] = (f32x4){0.f, 0.f, 0.f, 0.f};
        __builtin_amdgcn_s_setprio(1);
#pragma unroll
        for (int ks = 0; ks < 4; ++ks) {
#pragma unroll
            for (int nb = 0; nb < 2; ++nb) {
                int off = (nb * 16 + l16) * PK + ks * 32 + quad * 8;
                bf16x8 kh = *(const bf16x8*)&Kh[off];
                bf16x8 kl = *(const bf16x8*)&Kl[off];
                sacc[0][nb] = __builtin_amdgcn_mfma_f32_16x16x32_bf16(qh[0][ks], kh, sacc[0][nb], 0, 0, 0);
                sacc[0][nb] = __builtin_amdgcn_mfma_f32_16x16x32_bf16(qh[0][ks], kl, sacc[0][nb], 0, 0, 0);
                sacc[0][nb] = __builtin_amdgcn_mfma_f32_16x16x32_bf16(ql[0][ks], kh, sacc[0][nb], 0, 0, 0);
                sacc[1][nb] = __builtin_amdgcn_mfma_f32_16x16x32_bf16(qh[1][ks], kh, sacc[1][nb], 0, 0, 0);
                sacc[1][nb] = __builtin_amdgcn_mfma_f32_16x16x32_bf16(qh[1][ks], kl, sacc[1][nb], 0, 0, 0);
                sacc[1][nb] = __builtin_amdgcn_mfma_f32_16x16x32_bf16(ql[1][ks], kh, sacc[1][nb], 0, 0, 0);
            }
        }
        __builtin_amdgcn_s_setprio(0);

        // ---- online softmax (exp2 domain, defer-max THR=8, DPP reduce) ----
        float m0r[2][4];
        bool grow = false;
#pragma unroll
        for (int mb = 0; mb < 2; ++mb)
#pragma unroll
            for (int r = 0; r < 4; ++r) {
                float m0 = row16_max(fmaxf(sacc[mb][0][r], sacc[mb][1][r]));
                m0r[mb][r] = m0;
                grow |= (m0 - mrow[mb][r] > 8.0f);
            }
        if (__any(grow)) {
            // full rescale path (rare after the first few tiles)
#pragma unroll
            for (int mb = 0; mb < 2; ++mb)
#pragma unroll
                for (int r = 0; r < 4; ++r) {
                    float mnew  = fmaxf(mrow[mb][r], m0r[mb][r]);
                    float alpha = __builtin_amdgcn_exp2f(mrow[mb][r] - mnew);
                    mrow[mb][r] = mnew;
                    Lp[mb][r] *= alpha;
#pragma unroll
                    for (int d = 0; d < 8; ++d) O[mb][d][r] *= alpha;
                }
        }
        float p0[2][4], p1[2][4];
#pragma unroll
        for (int mb = 0; mb < 2; ++mb)
#pragma unroll
            for (int r = 0; r < 4; ++r) {
                float e0 = __builtin_amdgcn_exp2f(sacc[mb][0][r] - mrow[mb][r]);
                float e1 = __builtin_amdgcn_exp2f(sacc[mb][1][r] - mrow[mb][r]);
                p0[mb][r] = e0; p1[mb][r] = e1;
                Lp[mb][r] += e0 + e1;    // per-lane partial (2 cols)
            }

        // ---- P: C-layout regs -> wave-private LDS (A-layout read below) ----
        bf16* pw = &Ps[wave * 32 * PP];
#pragma unroll
        for (int mb = 0; mb < 2; ++mb)
#pragma unroll
            for (int r = 0; r < 4; ++r) {
                pw[(mb * 16 + quad * 4 + r) * PP + l16]      = (bf16)p0[mb][r];
                pw[(mb * 16 + quad * 4 + r) * PP + 16 + l16] = (bf16)p1[mb][r];
            }
        // same-wave DS RAW ordered via lgkmcnt by compiler

        // ---- PV: O[32 x 128] += P[32 x 32] * V[32 x 128]; vb shared ----
        {
            bf16x8 pa0 = *(const bf16x8*)&pw[l16 * PP + quad * 8];
            bf16x8 pa1 = *(const bf16x8*)&pw[(16 + l16) * PP + quad * 8];
            __builtin_amdgcn_s_setprio(1);
#pragma unroll
            for (int d = 0; d < 8; ++d) {
                bf16x8 vb = *(const bf16x8*)&Vs[(d * 16 + l16) * PVT + quad * 8];
                O[0][d] = __builtin_amdgcn_mfma_f32_16x16x32_bf16(pa0, vb, O[0][d], 0, 0, 0);
                O[1][d] = __builtin_amdgcn_mfma_f32_16x16x32_bf16(pa1, vb, O[1][d], 0, 0, 0);
            }
            __builtin_amdgcn_s_setprio(0);
        }

        if (it == NIT - 1) break;
        __syncthreads();            // all readers done with current tile
        WRITET();                   // stage tile it+1 (regs loaded last iter)
        if (it + 2 < NIT) LOADT(it + 2);   // in flight across next compute
        __syncthreads();            // tile it+1 visible
    }

    // ---- finalize: DPP-sum per-lane L over 16 l16-lanes, then store ----
    float rl[2][4];
#pragma unroll
    for (int mb = 0; mb < 2; ++mb)
#pragma unroll
        for (int r = 0; r < 4; ++r)
            rl[mb][r] = 1.0f / row16_sum(Lp[mb][r]);
    float* og = out + ((size_t)bh * S_ + (size_t)qt * BM + wave * 32) * D_;
#pragma unroll
    for (int mb = 0; mb < 2; ++mb)
#pragma unroll
        for (int d = 0; d < 8; ++d)
#pragma unroll
            for (int r = 0; r < 4; ++r)
                og[(mb * 16 + quad * 4 + r) * D_ + d * 16 + l16] =
                    O[mb][d][r] * rl[mb][r];
}

// ---- fallback: verified kernel (used if ws too small) ----
__global__ __launch_bounds__(256, 4) void attn_fwd_fb(
    const float* __restrict__ q, const float* __restrict__ kg,
    const float* __restrict__ vg, const float* __restrict__ sc,
    float* __restrict__ out)
{
    constexpr int FBM = 64;

    __shared__ __align__(16) bf16 Kh[BN * PK];
    __shared__ __align__(16) bf16 Kl[BN * PK];
    __shared__ __align__(16) bf16 Vs[D_ * PVT];
    __shared__ __align__(16) bf16 Ps2[4 * 16 * PP];

    const int tid  = threadIdx.x;
    const int wave = tid >> 6;
    const int lane = tid & 63;
    const int l16  = lane & 15;
    const int quad = lane >> 4;

    const int qt = blockIdx.x;
    const int bh = blockIdx.y;

    const float scale = sc[bh] * 1.44269504088896f;

    const float* qbase = q  + ((size_t)bh * S_ + (size_t)qt * FBM) * D_;
    const float* kbase = kg + (size_t)bh * S_ * D_;
    const float* vbase = vg + (size_t)bh * S_ * D_;

    bf16x8 qh[4], ql[4];
    {
        const float* qrow = qbase + (size_t)(wave * 16 + l16) * D_ + quad * 8;
#pragma unroll
        for (int ks = 0; ks < 4; ++ks) {
            float x[8];
            *(float4*)&x[0] = *(const float4*)(qrow + ks * 32);
            *(float4*)&x[4] = *(const float4*)(qrow + ks * 32 + 4);
#pragma unroll
            for (int j = 0; j < 8; ++j) {
                float xs = x[j] * scale;
                bf16 h = (bf16)xs;
                qh[ks][j] = h;
                ql[ks][j] = (bf16)(xs - (float)h);
            }
        }
    }

    f32x4 O[8];
#pragma unroll
    for (int i = 0; i < 8; ++i) O[i] = (f32x4){0.f, 0.f, 0.f, 0.f};
    float mrow[4] = {-1e30f, -1e30f, -1e30f, -1e30f};
    float Lp[4]   = {0.f, 0.f, 0.f, 0.f};

    for (int it = 0; it < NIT; ++it) {
        __syncthreads();
        {
            const float* kt = kbase + (size_t)it * BN * D_;
#pragma unroll
            for (int r = 0; r < 4; ++r) {
                int i = tid + r * 256;
                int row = i >> 5, c = i & 31;
                float4 v = *(const float4*)(kt + row * D_ + c * 4);
                const float* x = (const float*)&v;
                bf16x4 h4, l4;
#pragma unroll
                for (int j = 0; j < 4; ++j) {
                    bf16 h = (bf16)x[j];
                    h4[j] = h;
                    l4[j] = (bf16)(x[j] - (float)h);
                }
                *(bf16x4*)&Kh[row * PK + c * 4] = h4;
                *(bf16x4*)&Kl[row * PK + c * 4] = l4;
            }
            const float* vt = vbase + (size_t)it * BN * D_;
#pragma unroll
            for (int r = 0; r < 2; ++r) {
                int i = tid + r * 256;
                int p = i & 15;
                int c = i >> 4;
                const float* v0 = vt + (2 * p) * D_ + c * 4;
                float4 a0 = *(const float4*)v0;
                float4 a1 = *(const float4*)(v0 + D_);
                const float* x0 = (const float*)&a0;
                const float* x1 = (const float*)&a1;
#pragma unroll
                for (int j = 0; j < 4; ++j) {
                    union { ushort2 u; bf16 b[2]; } pr;
                    pr.b[0] = (bf16)x0[j];
                    pr.b[1] = (bf16)x1[j];
                    *(ushort2*)&Vs[(c * 4 + j) * PVT + 2 * p] = pr.u;
                }
            }
        }
        __syncthreads();

        f32x4 sacc[2];
        sacc[0] = (f32x4){0.f, 0.f, 0.f, 0.f};
        sacc[1] = (f32x4){0.f, 0.f, 0.f, 0.f};
#pragma unroll
        for (int ks = 0; ks < 4; ++ks) {
#pragma unroll
            for (int nb = 0; nb < 2; ++nb) {
                int off = (nb * 16 + l16) * PK + ks * 32 + quad * 8;
                bf16x8 kh = *(const bf16x8*)&Kh[off];
                bf16x8 kl = *(const bf16x8*)&Kl[off];
                sacc[nb] = __builtin_amdgcn_mfma_f32_16x16x32_bf16(qh[ks], kh, sacc[nb], 0, 0, 0);
                sacc[nb] = __builtin_amdgcn_mfma_f32_16x16x32_bf16(qh[ks], kl, sacc[nb], 0, 0, 0);
                sacc[nb] = __builtin_amdgcn_mfma_f32_16x16x32_bf16(ql[ks], kh, sacc[nb], 0, 0, 0);
            }
        }

        float p0[4], p1[4];
#pragma unroll
        for (int r = 0; r < 4; ++r) {
            float m0 = fmaxf(sacc[0][r], sacc[1][r]);
#pragma unroll
            for (int off = 8; off >= 1; off >>= 1)
                m0 = fmaxf(m0, __shfl_xor(m0, off, 64));
            float mnew  = fmaxf(mrow[r], m0);
            float alpha = __builtin_amdgcn_exp2f(mrow[r] - mnew);
            mrow[r] = mnew;
            float e0 = __builtin_amdgcn_exp2f(sacc[0][r] - mnew);
            float e1 = __builtin_amdgcn_exp2f(sacc[1][r] - mnew);
            p0[r] = e0; p1[r] = e1;
            Lp[r] = Lp[r] * alpha + (e0 + e1);
#pragma unroll
            for (int d = 0; d < 8; ++d) O[d][r] *= alpha;
        }

        bf16* pw = &Ps2[wave * 16 * PP];
#pragma unroll
        for (int r = 0; r < 4; ++r) {
            pw[(quad * 4 + r) * PP + l16]      = (bf16)p0[r];
            pw[(quad * 4 + r) * PP + 16 + l16] = (bf16)p1[r];
        }
        {
            bf16x8 pa = *(const bf16x8*)&pw[l16 * PP + quad * 8];
#pragma unroll
            for (int d = 0; d < 8; ++d) {
                bf16x8 vb = *(const bf16x8*)&Vs[(d * 16 + l16) * PVT + quad * 8];
                O[d] = __builtin_amdgcn_mfma_f32_16x16x32_bf16(pa, vb, O[d], 0, 0, 0);
            }
        }
    }

    float rl[4];
#pragma unroll
    for (int r = 0; r < 4; ++r) {
        float L = Lp[r];
#pragma unroll
        for (int off = 8; off >= 1; off >>= 1)
            L += __shfl_xor(L, off, 64);
        rl[r] = 1.0f / L;
    }
    float* og = out + ((size_t)bh * S_ + (size_t)qt * FBM + wave * 16) * D_;
#pragma unroll
    for (int d = 0; d < 8; ++d)
#pragma unroll
        for (int r = 0; r < 4; ++r)
            og[(quad * 4 + r) * D_ + d * 16 + l16] = O[d][r] * rl[r];
}

extern "C" void kernel_launch(void* const* d_in, const int* in_sizes, int n_in,
                              void* d_out, int out_size, void* d_ws, size_t ws_size,
                              hipStream_t stream) {
    const float* q  = (const float*)d_in[0];
    const float* k  = (const float*)d_in[1];
    const float* v  = (const float*)d_in[2];
    const float* sc = (const float*)d_in[3];
    float* o = (float*)d_out;
    if (d_ws && ws_size >= WS_NEED) {
        bf16* ws = (bf16*)d_ws;
        prepack<<<16384, 256, 0, stream>>>(k, v, ws);          // ~60 us
        attn_fwd<<<1024, 256, 0, stream>>>(q, ws, sc, o);
    } else {
        attn_fwd_fb<<<dim3(S_ / 64, 64), 256, 0, stream>>>(q, k, v, sc, o);
    }
}